// Round 8
// baseline (697.809 us; speedup 1.0000x reference)
//
#include <hip/hip_runtime.h>

// T=4, B=16, C=768, H=W=16 -> N=256, Ch=3072, heads=12, d=64
#define T_ 4
#define B_ 16
#define C_ 768
#define N_ 256
#define CH_ 3072

typedef _Float16 f16x8 __attribute__((ext_vector_type(8)));
typedef _Float16 f16x4 __attribute__((ext_vector_type(4)));
typedef float f32x4 __attribute__((ext_vector_type(4)));

// ---------------------------------------------------------------------------
// Blocked operand layout (A=weights, B=activations):
//   per 128(row) x 32(k) tile: 512 chunks of 8 halfs (16B).
//   chunk index c = k8*128 + row; chunk holds k = kt*32 + k8*8 + (0..7).
// A arrays: [mb][KT][512]; B arrays: [bt][nb(2)][KT][512].
// Staging is lane-linear in the LDS dest (global_load_lds rule); the GLOBAL
// source may be arbitrary per-lane (used by the 32-row A-subtile staging).
// frag ds_read_b128 is bank-optimal (SQ_LDS_BANK_CONFLICT == 0 measured).
//
// XCD swizzle (R4: FETCH -11%): bijective chunked remap
//   l = (l0 % 8) * (ntot/8) + l0 / 8,   decode (nb, mid, hi).
//
// Structure (R7 post-mortem: fusion mechanism good, geometry bad):
//   qk   : per-bt 256-thr gemm_mfma, 1536 blocks, 2 blocks/CU (best measured)
//   mlp1 : t-batched 8-wave, fused BN+LIF epilogue (R4 structure, 189 us)
//   p,z2 : t-batched FUSED kernels with M=32 tiles -> grid 768 blocks
//          (3 balanced CU rounds), LDS 72 KB dbuf -> 2 blocks/CU, regs
//          pinned <=128/wave. Fusion deletes p_pre/z2 fp32 round-trips
//          (~200 MB) and two launches; 2-block residency restores overlap.
// ---------------------------------------------------------------------------

__device__ __forceinline__ int xcd_swizzle_linear()
{
    const int ntot = gridDim.x * gridDim.y * gridDim.z;
    const int l0 = blockIdx.x + gridDim.x * (blockIdx.y + gridDim.y * blockIdx.z);
    return (l0 & 7) * (ntot >> 3) + (l0 >> 3);   // ntot % 8 == 0 for all launches
}

// 4-wave staging: each wave stages 128 chunks (2 x 16B/lane instrs).
__device__ __forceinline__ void stage_tile(const _Float16* g, _Float16* l,
                                           int wv, int ln)
{
#pragma unroll
    for (int i = 0; i < 2; ++i) {
        const int c = wv * 128 + i * 64;
        __builtin_amdgcn_global_load_lds(
            (const __attribute__((address_space(1))) void*)(g + (size_t)(c + ln) * 8),
            (__attribute__((address_space(3))) void*)(l + (size_t)c * 8),
            16, 0, 0);
    }
}

// 8-wave staging: each wave stages 64 chunks (1 x 16B/lane instr).
__device__ __forceinline__ void stage_tile8(const _Float16* g, _Float16* l,
                                            int wv, int ln)
{
    const int c = wv * 64;
    __builtin_amdgcn_global_load_lds(
        (const __attribute__((address_space(1))) void*)(g + (size_t)(c + ln) * 8),
        (__attribute__((address_space(3))) void*)(l + (size_t)c * 8),
        16, 0, 0);
}

// ---------------------------------------------------------------------------
// Per-bt MFMA GEMM (qk path): O[bt, m, n] = oscale * sum_k (A0+A1)*(B0,B1)
// NB=2: general fp32 operand (A0B0, A1B0, A0B1).
// Tile 128x128, 4 waves of 64x64 (4x4 mfma_f32_16x16x32_f16), dbuf stage-ahead.
// Dual output: by < splitBy -> Oq, else Ok (m rebased). M = rows per output.
// ---------------------------------------------------------------------------
template <int NB, int ORD>
__global__ __launch_bounds__(256) void gemm_mfma(
    const _Float16* __restrict__ A0, const _Float16* __restrict__ A1,
    const _Float16* __restrict__ B0, const _Float16* __restrict__ B1,
    float* __restrict__ Oq, float* __restrict__ Ok, int splitBy, int M,
    const float* __restrict__ bias, float oscale,
    int KTA, int ktA0, int mbA0, int KTB, int nkt, int midN)
{
    const int l = xcd_swizzle_linear();
    const int nb = l & 1;
    const int mid = (l >> 1) % midN;
    const int hi  = (l >> 1) / midN;
    const int by = (ORD == 0) ? mid : hi;
    const int bt = (ORD == 0) ? hi  : mid;
    const int mbA = mbA0 + by;

    __shared__ _Float16 lds[2][(2 + NB) * 4096];

    const int tid = threadIdx.x;
    const int wv = tid >> 6;
    const int ln = tid & 63;
    const int mw = (wv >> 1) * 64;
    const int nw = (wv & 1) * 64;

    f32x4 acc[4][4];
#pragma unroll
    for (int i = 0; i < 4; ++i)
#pragma unroll
        for (int j = 0; j < 4; ++j)
            acc[i][j] = (f32x4){0.f, 0.f, 0.f, 0.f};

    const _Float16* ga0 = A0 + ((size_t)mbA * KTA + ktA0) * 4096;
    const _Float16* ga1 = A1 + ((size_t)mbA * KTA + ktA0) * 4096;
    const _Float16* gb0 = B0 + (((size_t)bt * 2 + nb) * KTB) * 4096;
    const _Float16* gb1 = (NB == 2) ? B1 + (((size_t)bt * 2 + nb) * KTB) * 4096 : nullptr;

    const int ca = (ln >> 4) * 128 + mw + (ln & 15);   // A frag chunk base
    const int cb = (ln >> 4) * 128 + nw + (ln & 15);   // B frag chunk base

    _Float16* Lc = &lds[0][0];
    _Float16* Ln = &lds[1][0];

    // prologue: stage kt=0 into buffer 0
    stage_tile(ga0, Lc, wv, ln);
    stage_tile(ga1, Lc + 4096, wv, ln);
    stage_tile(gb0, Lc + 2 * 4096, wv, ln);
    if (NB == 2) stage_tile(gb1, Lc + 3 * 4096, wv, ln);

    for (int kt = 0; kt < nkt; ++kt) {
        __syncthreads();   // drains vmcnt: Lc staged; fences last iter's Ln reads
        if (kt + 1 < nkt) {
            stage_tile(ga0 + 4096, Ln, wv, ln);
            stage_tile(ga1 + 4096, Ln + 4096, wv, ln);
            stage_tile(gb0 + 4096, Ln + 2 * 4096, wv, ln);
            if (NB == 2) stage_tile(gb1 + 4096, Ln + 3 * 4096, wv, ln);
        }

        f16x8 a0[4], a1[4];
#pragma unroll
        for (int mt = 0; mt < 4; ++mt) {
            a0[mt] = *(const f16x8*)&Lc[(ca + mt * 16) * 8];
            a1[mt] = *(const f16x8*)&Lc[4096 + (ca + mt * 16) * 8];
        }
#pragma unroll
        for (int nt = 0; nt < 4; ++nt) {
            const f16x8 b0 = *(const f16x8*)&Lc[2 * 4096 + (cb + nt * 16) * 8];
            f16x8 b1;
            if (NB == 2) b1 = *(const f16x8*)&Lc[3 * 4096 + (cb + nt * 16) * 8];
#pragma unroll
            for (int mt = 0; mt < 4; ++mt) {
                acc[mt][nt] = __builtin_amdgcn_mfma_f32_16x16x32_f16(a0[mt], b0, acc[mt][nt], 0, 0, 0);
                acc[mt][nt] = __builtin_amdgcn_mfma_f32_16x16x32_f16(a1[mt], b0, acc[mt][nt], 0, 0, 0);
                if (NB == 2)
                    acc[mt][nt] = __builtin_amdgcn_mfma_f32_16x16x32_f16(a0[mt], b1, acc[mt][nt], 0, 0, 0);
            }
        }
        ga0 += 4096; ga1 += 4096; gb0 += 4096;
        if (NB == 2) gb1 += 4096;
        _Float16* tmp = Lc; Lc = Ln; Ln = tmp;
    }

    // Epilogue. C/D layout: col(n) = lane&15, row(m) = (lane>>4)*4 + reg.
    float* Obase = (by < splitBy) ? Oq : Ok;
    const int byl = (by < splitBy) ? by : by - splitBy;
    float* Ob = Obase + (size_t)bt * M * 256;
    const int lm = (ln >> 4) * 4;
    const int lnn = ln & 15;
#pragma unroll
    for (int mt = 0; mt < 4; ++mt) {
#pragma unroll
        for (int r = 0; r < 4; ++r) {
            const int m = byl * 128 + mw + mt * 16 + lm + r;
            const float bb = bias ? bias[m] : 0.0f;
#pragma unroll
            for (int nt = 0; nt < 4; ++nt) {
                const int n = nb * 128 + nw + nt * 16 + lnn;
                Ob[(size_t)m * 256 + n] = acc[mt][nt][r] * oscale + bb;
            }
        }
    }
}

// ---------------------------------------------------------------------------
// t-batched spike GEMM with fused LIF epilogue, M=32 row tile.
// Grid (2, 24, 16) = 768 blocks (3 balanced CU rounds), 512 threads, 8 waves.
// Per block: rows [by*32, +32), cols nb*128 + [0,128), ALL 4 t.
// Wave wv owns 16 cols (nw = wv*16) x 32 rows x 4 t: 16 MFMA per kt.
// LDS per kt: A0sub,A1sub (2x2KB, 32-row subtiles) + 4t x B (4x8KB) = 36 KB;
// x2 dbuf = 72 KB -> 2 blocks/CU. acc[4][2] = 32 VGPR; launch_bounds (512,4)
// pins combined regs <= 128/wave so 16 waves/CU are resident.
// A-subtile staging: per-lane GLOBAL src chunk (w*2+(ln>>5))*128 + rowbase +
// (ln&31); LDS dest lane-linear [k8][32][8].
// MODE 0 (p path):  u = BN_p(acc*oscale + bias); LIF -> sp;
//                   y = x + sp; write scaled fp16 split (Y0,Y1).
// MODE 1 (z2 path): u = BN_2(acc*oscale + bias); LIF -> sp;
//                   out = (Y0+Y1)*yinv + sp  (fp32).
// ---------------------------------------------------------------------------
template <int MODE>
__global__ __launch_bounds__(512, 4) void gemm_tb_lif32(
    const _Float16* __restrict__ A0, const _Float16* __restrict__ A1,
    const _Float16* __restrict__ B0,
    const float* __restrict__ bias, const float* __restrict__ bnp,
    float oscale, int KT, int nkt,
    const float* __restrict__ x,                 // MODE 0: residual input
    _Float16* __restrict__ Y0, _Float16* __restrict__ Y1,  // MODE0: out, MODE1: in
    float* __restrict__ outp,                    // MODE 1: final output
    float sc2)                                   // MODE0: xscale, MODE1: yinv
{
    const int l = xcd_swizzle_linear();          // 768 blocks
    const int nb = l & 1;
    const int by = (l >> 1) % 24;                // row block (32 rows)
    const int b  = (l >> 1) / 24;

    // LDS chunk map: A0sub [0,128), A1sub [128,256), B_t [256+t*512, +512)
    __shared__ _Float16 lds[2][2304 * 8];        // 2 x 36 KB

    const int tid = threadIdx.x;
    const int wv = tid >> 6;              // 0..7
    const int ln = tid & 63;
    const int nw = wv * 16;               // 16-col group per wave
    const int lm = (ln >> 4) * 4;
    const int lnn = ln & 15;

    const int mbA = by >> 2;
    const int rowbase = (by & 3) * 32;

    const _Float16* gA0 = A0 + ((size_t)mbA * KT) * 4096;
    const _Float16* gA1 = A1 + ((size_t)mbA * KT) * 4096;
    const _Float16* gBt = B0 + (((size_t)((wv >> 1) * B_ + b) * 2 + nb) * KT) * 4096;

    f32x4 acc[4][2];                      // [t][mt]
#pragma unroll
    for (int t = 0; t < 4; ++t)
#pragma unroll
        for (int i = 0; i < 2; ++i)
            acc[t][i] = (f32x4){0.f, 0.f, 0.f, 0.f};

    // A frag: chunk (ln>>4)*32 + mt*16 + (ln&15);  B frag: 256+t*512+(ln>>4)*128+nw+(ln&15)
    const int caf = (ln >> 4) * 32 + lnn;
    const int cbf = (ln >> 4) * 128 + nw + lnn;

    // A-subtile staging source chunk (per-lane, w = half index 0/1):
    const int wA = wv & 1;
    const int srcA = ((wA * 2 + (ln >> 5)) * 128) + rowbase + (ln & 31);
    const int dstA = (wv < 2 ? 0 : 128) + wA * 64;     // A0 halves / A1 halves
    const int tB = wv >> 1, hb = wv & 1;

    _Float16* Lc = &lds[0][0];
    _Float16* Ln = &lds[1][0];

    // prologue: stage kt=0 into buffer 0
    {
        if (wv < 4) {
            const _Float16* ga = (wv < 2) ? gA0 : gA1;
            __builtin_amdgcn_global_load_lds(
                (const __attribute__((address_space(1))) void*)(ga + (size_t)srcA * 8),
                (__attribute__((address_space(3))) void*)(Lc + (size_t)dstA * 8),
                16, 0, 0);
        }
#pragma unroll
        for (int i = 0; i < 4; ++i) {
            const int c = hb * 256 + i * 64;
            __builtin_amdgcn_global_load_lds(
                (const __attribute__((address_space(1))) void*)(gBt + (size_t)(c + ln) * 8),
                (__attribute__((address_space(3))) void*)(Lc + (size_t)(256 + tB * 512 + c) * 8),
                16, 0, 0);
        }
    }

    for (int kt = 0; kt < nkt; ++kt) {
        __syncthreads();   // drains vmcnt: Lc staged; fences last iter's Ln reads
        if (kt + 1 < nkt) {
            const size_t o = (size_t)(kt + 1) * 4096;
            if (wv < 4) {
                const _Float16* ga = ((wv < 2) ? gA0 : gA1) + o;
                __builtin_amdgcn_global_load_lds(
                    (const __attribute__((address_space(1))) void*)(ga + (size_t)srcA * 8),
                    (__attribute__((address_space(3))) void*)(Ln + (size_t)dstA * 8),
                    16, 0, 0);
            }
#pragma unroll
            for (int i = 0; i < 4; ++i) {
                const int c = hb * 256 + i * 64;
                __builtin_amdgcn_global_load_lds(
                    (const __attribute__((address_space(1))) void*)(gBt + o + (size_t)(c + ln) * 8),
                    (__attribute__((address_space(3))) void*)(Ln + (size_t)(256 + tB * 512 + c) * 8),
                    16, 0, 0);
            }
        }

        f16x8 a0[2], a1[2];
#pragma unroll
        for (int mt = 0; mt < 2; ++mt) {
            a0[mt] = *(const f16x8*)&Lc[(caf + mt * 16) * 8];
            a1[mt] = *(const f16x8*)&Lc[(128 + caf + mt * 16) * 8];
        }
#pragma unroll
        for (int t = 0; t < 4; ++t) {
            const f16x8 b0 = *(const f16x8*)&Lc[(256 + t * 512 + cbf) * 8];
#pragma unroll
            for (int mt = 0; mt < 2; ++mt) {
                acc[t][mt] = __builtin_amdgcn_mfma_f32_16x16x32_f16(a0[mt], b0, acc[t][mt], 0, 0, 0);
                acc[t][mt] = __builtin_amdgcn_mfma_f32_16x16x32_f16(a1[mt], b0, acc[t][mt], 0, 0, 0);
            }
        }
        _Float16* tmp = Lc; Lc = Ln; Ln = tmp;
    }

    // folded BN: u = acc*(oscale*sc) + ((bias-mu)*sc + be)   (Cs = C_)
    float Af[8], Bf[8];
#pragma unroll
    for (int mt = 0; mt < 2; ++mt)
#pragma unroll
        for (int r = 0; r < 4; ++r) {
            const int c = by * 32 + mt * 16 + lm + r;
            const float g  = bnp[c];
            const float be = bnp[C_ + c];
            const float mu = bnp[2 * C_ + c];
            const float va = bnp[3 * C_ + c];
            const float sc = g * rsqrtf(va + 1e-5f);
            Af[mt * 4 + r] = oscale * sc;
            Bf[mt * 4 + r] = (bias[c] - mu) * sc + be;
        }

    // LIF over t, per lane's 4 channels x 2 m-tiles (C/D: col=ln&15, row=(ln>>4)*4+r)
    const int rowN = nw + lnn;            // n within nb*128
    const int n = nb * 128 + rowN;
#pragma unroll
    for (int mt = 0; mt < 2; ++mt) {
        const int c0m = by * 32 + mt * 16 + lm;         // lane's first channel
        const int kt_out = c0m >> 5;
        const int k8y = (c0m & 31) >> 3;
        const int j0 = c0m & 7;                         // 0 or 4
        float vv[4] = {0.f, 0.f, 0.f, 0.f};
#pragma unroll
        for (int t = 0; t < 4; ++t) {
            const int bt = t * B_ + b;
            const size_t ycb = (((size_t)bt * 2 + nb) * 24 + kt_out) * 4096
                               + ((size_t)k8y * 128 + rowN) * 8 + j0;
            if (MODE == 0) {
                f16x4 h0, h1;
#pragma unroll
                for (int r = 0; r < 4; ++r) {
                    const float u = acc[t][mt][r] * Af[mt * 4 + r] + Bf[mt * 4 + r];
                    float xv = vv[r];
                    xv = xv + (u - xv) * 0.5f;
                    const float sp = (xv >= 1.0f) ? 1.0f : 0.0f;
                    vv[r] = (sp > 0.0f) ? 0.0f : xv;
                    const float xr = x[((size_t)bt * C_ + c0m + r) * 256 + n];
                    const float ys = (xr + sp) * sc2;
                    const _Float16 hh = (_Float16)ys;
                    h0[r] = hh;
                    h1[r] = (_Float16)(ys - (float)hh);
                }
                *(f16x4*)(Y0 + ycb) = h0;
                *(f16x4*)(Y1 + ycb) = h1;
            } else {
                const f16x4 y0 = *(const f16x4*)(Y0 + ycb);
                const f16x4 y1 = *(const f16x4*)(Y1 + ycb);
#pragma unroll
                for (int r = 0; r < 4; ++r) {
                    const float u = acc[t][mt][r] * Af[mt * 4 + r] + Bf[mt * 4 + r];
                    float xv = vv[r];
                    xv = xv + (u - xv) * 0.5f;
                    const float sp = (xv >= 1.0f) ? 1.0f : 0.0f;
                    vv[r] = (sp > 0.0f) ? 0.0f : xv;
                    const float y = ((float)y0[r] + (float)y1[r]) * sc2;
                    outp[((size_t)bt * C_ + c0m + r) * 256 + n] = y + sp;
                }
            }
        }
    }
}

// ---------------------------------------------------------------------------
// Fused MLP layer-1 (R4 structure — best measured, 189 us): s1 =
// LIF(BN1(w1 @ y + b1)), all 4 t in one K-pass; 8 waves, 96 MFMA/window;
// LDS 2 x 80 KB dbuf stage-ahead; BN+LIF epilogue -> blocked fp16 spikes.
// ---------------------------------------------------------------------------
__global__ __launch_bounds__(512, 2) void gemm_mlp1(
    const _Float16* __restrict__ A0, const _Float16* __restrict__ A1,
    const _Float16* __restrict__ B0, const _Float16* __restrict__ B1,
    const float* __restrict__ bias, const float* __restrict__ bnp,
    _Float16* __restrict__ outB, float oscale)
{
    const int l = xcd_swizzle_linear();            // 768 blocks, chunk=96/XCD
    const int nb = l & 1;                          // 0..1
    const int by = (l >> 1) % 24;                  // 0..23
    const int b  = (l >> 1) / 24;                  // 0..15

    __shared__ _Float16 lds[2][10 * 4096];   // 163840 B = full 160 KiB LDS

    const int tid = threadIdx.x;
    const int wv = tid >> 6;              // 0..7
    const int ln = tid & 63;
    const int mw = (wv >> 2) * 64;        // 2 m-groups of 64
    const int nw = (wv & 3) * 32;         // 4 n-groups of 32
    const int lm = (ln >> 4) * 4;
    const int lnn = ln & 15;

    const _Float16* gA0 = A0 + ((size_t)by * 24) * 4096;
    const _Float16* gA1 = A1 + ((size_t)by * 24) * 4096;
    const _Float16* gB0t[4];
    const _Float16* gB1t[4];
#pragma unroll
    for (int t = 0; t < 4; ++t) {
        const int bt = t * B_ + b;
        gB0t[t] = B0 + (((size_t)bt * 2 + nb) * 24) * 4096;
        gB1t[t] = B1 + (((size_t)bt * 2 + nb) * 24) * 4096;
    }

    f32x4 acc[4][4][2];                   // [t][mt][nt]
#pragma unroll
    for (int t = 0; t < 4; ++t)
#pragma unroll
        for (int i = 0; i < 4; ++i)
#pragma unroll
            for (int j = 0; j < 2; ++j)
                acc[t][i][j] = (f32x4){0.f, 0.f, 0.f, 0.f};

    const int ca = (ln >> 4) * 128 + mw + lnn;   // A frag chunk base
    const int cb = (ln >> 4) * 128 + nw + lnn;   // B frag chunk base

    _Float16* Lc = &lds[0][0];
    _Float16* Ln = &lds[1][0];

    // prologue: stage kt=0
    stage_tile8(gA0, Lc, wv, ln);
    stage_tile8(gA1, Lc + 4096, wv, ln);
#pragma unroll
    for (int t = 0; t < 4; ++t) {
        stage_tile8(gB0t[t], Lc + (2 + 2 * t) * 4096, wv, ln);
        stage_tile8(gB1t[t], Lc + (3 + 2 * t) * 4096, wv, ln);
    }

    for (int kt = 0; kt < 24; ++kt) {
        __syncthreads();   // drains vmcnt: Lc staged; fences last iter's Ln reads
        if (kt < 23) {
            const size_t o = (size_t)(kt + 1) * 4096;
            stage_tile8(gA0 + o, Ln, wv, ln);
            stage_tile8(gA1 + o, Ln + 4096, wv, ln);
#pragma unroll
            for (int t = 0; t < 4; ++t) {
                stage_tile8(gB0t[t] + o, Ln + (2 + 2 * t) * 4096, wv, ln);
                stage_tile8(gB1t[t] + o, Ln + (3 + 2 * t) * 4096, wv, ln);
            }
        }

        f16x8 a0[4], a1[4];
#pragma unroll
        for (int mt = 0; mt < 4; ++mt) {
            a0[mt] = *(const f16x8*)&Lc[(ca + mt * 16) * 8];
            a1[mt] = *(const f16x8*)&Lc[4096 + (ca + mt * 16) * 8];
        }
#pragma unroll
        for (int t = 0; t < 4; ++t) {
#pragma unroll
            for (int nt = 0; nt < 2; ++nt) {
                const f16x8 b0 = *(const f16x8*)&Lc[(2 + 2 * t) * 4096 + (cb + nt * 16) * 8];
                const f16x8 b1 = *(const f16x8*)&Lc[(3 + 2 * t) * 4096 + (cb + nt * 16) * 8];
#pragma unroll
                for (int mt = 0; mt < 4; ++mt) {
                    acc[t][mt][nt] = __builtin_amdgcn_mfma_f32_16x16x32_f16(a0[mt], b0, acc[t][mt][nt], 0, 0, 0);
                    acc[t][mt][nt] = __builtin_amdgcn_mfma_f32_16x16x32_f16(a1[mt], b0, acc[t][mt][nt], 0, 0, 0);
                    acc[t][mt][nt] = __builtin_amdgcn_mfma_f32_16x16x32_f16(a0[mt], b1, acc[t][mt][nt], 0, 0, 0);
                }
            }
        }
        _Float16* tmp = Lc; Lc = Ln; Ln = tmp;
    }

    // folded BN constants: u = acc*(oscale*sc) + ((bias-mu)*sc + be)
    float Af[16], Bf[16];
#pragma unroll
    for (int mt = 0; mt < 4; ++mt)
#pragma unroll
        for (int r = 0; r < 4; ++r) {
            const int c = by * 128 + mw + mt * 16 + lm + r;
            const float g  = bnp[c];
            const float be = bnp[CH_ + c];
            const float mu = bnp[2 * CH_ + c];
            const float va = bnp[3 * CH_ + c];
            const float sc = g * rsqrtf(va + 1e-5f);
            Af[mt * 4 + r] = oscale * sc;
            Bf[mt * 4 + r] = (bias[c] - mu) * sc + be;
        }

    // BN + LIF over t -> blocked fp16 spikes (s1B, KT=96)
#pragma unroll
    for (int mt = 0; mt < 4; ++mt) {
        const int c0m = by * 128 + mw + mt * 16 + lm;   // lane's first channel
        const int kt_out = c0m >> 5;
        const int k8 = (c0m & 31) >> 3;
        const int j0 = c0m & 7;                         // 0 or 4
#pragma unroll
        for (int nt = 0; nt < 2; ++nt) {
            const int row = nw + nt * 16 + lnn;
            float vv[4] = {0.f, 0.f, 0.f, 0.f};
#pragma unroll
            for (int t = 0; t < 4; ++t) {
                const int bt = t * B_ + b;
                _Float16* ob = outB + (((size_t)bt * 2 + nb) * 96) * 4096;
                f16x4 hh;
#pragma unroll
                for (int r = 0; r < 4; ++r) {
                    const float u = acc[t][mt][nt][r] * Af[mt * 4 + r] + Bf[mt * 4 + r];
                    float xv = vv[r];
                    xv = xv + (u - xv) * 0.5f;
                    const float sp = (xv >= 1.0f) ? 1.0f : 0.0f;
                    vv[r] = (sp > 0.0f) ? 0.0f : xv;
                    hh[r] = (_Float16)sp;
                }
                *(f16x4*)(ob + ((size_t)kt_out * 512 + k8 * 128 + row) * 8 + j0) = hh;
            }
        }
    }
}

// ---------------------------------------------------------------------------
// Merged weight split for w1 (576 block-units) + w2 (576): one launch.
// bi < 576: w1 [3072][768], KT=24, mb=bi%24;  else w2 [768][3072], KT=96.
// ---------------------------------------------------------------------------
__global__ void splitW12(const float* __restrict__ w1s, const float* __restrict__ w2s,
                         _Float16* __restrict__ C10, _Float16* __restrict__ C11,
                         _Float16* __restrict__ C20, _Float16* __restrict__ C21,
                         float scale)
{
    const int bi = blockIdx.x;
    const float* W; _Float16 *C0, *C1; int mb, kt, KT, ldW;
    if (bi < 576) { W = w1s; C0 = C10; C1 = C11; mb = bi % 24; kt = bi / 24; KT = 24; ldW = C_; }
    else          { const int bj = bi - 576;
                    W = w2s; C0 = C20; C1 = C21; mb = bj % 6;  kt = bj / 6;  KT = 96; ldW = CH_; }
    const int mm = threadIdx.x, k8 = threadIdx.y;
    const float* src = W + (size_t)(mb * 128 + mm) * ldW + kt * 32 + k8 * 8;
    const size_t cb = (((size_t)mb * KT + kt) * 512 + k8 * 128 + mm) * 8;
    f16x8 h0, h1;
#pragma unroll
    for (int j = 0; j < 8; ++j) {
        const float x = src[j] * scale;
        const _Float16 h = (_Float16)x;
        h0[j] = h;
        h1[j] = (_Float16)(x - (float)h);
    }
    *(f16x8*)(C0 + cb) = h0;
    *(f16x8*)(C1 + cb) = h1;
}

// ---------------------------------------------------------------------------
// Merged split of the three CxC weights: z=0 -> w_q (WQK rows 0..767),
// z=1 -> w_k (WQK rows 768..1535), z=2 -> w_p. grid (6, 24, 3), block (128,4).
// ---------------------------------------------------------------------------
__global__ void splitW3(const float* __restrict__ wq, const float* __restrict__ wk,
                        const float* __restrict__ wp,
                        _Float16* __restrict__ WQK0, _Float16* __restrict__ WQK1,
                        _Float16* __restrict__ WP0,  _Float16* __restrict__ WP1,
                        float scale)
{
    const size_t WCC = (size_t)C_ * C_;
    const int z = blockIdx.z;
    const float* W;
    _Float16 *C0, *C1;
    if (z == 0)      { W = wq; C0 = WQK0;       C1 = WQK1; }
    else if (z == 1) { W = wk; C0 = WQK0 + WCC; C1 = WQK1 + WCC; }
    else             { W = wp; C0 = WP0;        C1 = WP1; }
    const int mb = blockIdx.x, kt = blockIdx.y;
    const int mm = threadIdx.x, k8 = threadIdx.y;
    const float* src = W + (size_t)(mb * 128 + mm) * C_ + kt * 32 + k8 * 8;
    const size_t cb = (((size_t)mb * 24 + kt) * 512 + k8 * 128 + mm) * 8;
    f16x8 h0, h1;
#pragma unroll
    for (int j = 0; j < 8; ++j) {
        const float x = src[j] * scale;
        const _Float16 h = (_Float16)x;
        h0[j] = h;
        h1[j] = (_Float16)(x - (float)h);
    }
    *(f16x8*)(C0 + cb) = h0;
    *(f16x8*)(C1 + cb) = h1;
}

// ---------------------------------------------------------------------------
// Activation split: X fp32 [64][K][256] -> 2 fp16 chunk arrays (blocked B),
// scaled by 2^8. grid (2, KT, 64), block (128,4).
// ---------------------------------------------------------------------------
__global__ void splitB(const float* __restrict__ X,
                       _Float16* __restrict__ C0, _Float16* __restrict__ C1,
                       int KT, float scale)
{
    const int nb = blockIdx.x, kt = blockIdx.y, bt = blockIdx.z;
    const int nn = threadIdx.x, k8 = threadIdx.y;
    const int K = KT * 32;
    const float* src = X + ((size_t)bt * K + kt * 32 + k8 * 8) * 256 + nb * 128 + nn;
    const size_t cb = ((((size_t)bt * 2 + nb) * KT + kt) * 512 + k8 * 128 + nn) * 8;
    f16x8 h0, h1;
#pragma unroll
    for (int j = 0; j < 8; ++j) {
        const float x = src[(size_t)j * 256] * scale;
        const _Float16 h = (_Float16)x;
        h0[j] = h;
        h1[j] = (_Float16)(x - (float)h);
    }
    *(f16x8*)(C0 + cb) = h0;
    *(f16x8*)(C1 + cb) = h1;
}

// ---------------------------------------------------------------------------
// Fused q path: BN+LIF on q_pre, head-sum over d=64, attn LIF -> attn spikes.
// q spikes never materialized. grid (4, 12, 16), block (64, 8).
// ---------------------------------------------------------------------------
__global__ __launch_bounds__(512) void qattn_kernel(
    const float* __restrict__ qpre, const float* __restrict__ bnp,
    float* __restrict__ attn)
{
    const int tx = threadIdx.x, ty = threadIdx.y;
    const int n = blockIdx.x * 64 + tx;
    const int h = blockIdx.y, b = blockIdx.z;
    __shared__ float red[8][64];

    float sc[8], be[8], mu[8];
#pragma unroll
    for (int j = 0; j < 8; ++j) {
        const int c = h * 64 + ty * 8 + j;
        const float g = bnp[c];
        be[j] = bnp[C_ + c];
        mu[j] = bnp[2 * C_ + c];
        sc[j] = g * rsqrtf(bnp[3 * C_ + c] + 1e-5f);
    }
    float v[8];
#pragma unroll
    for (int j = 0; j < 8; ++j) v[j] = 0.f;
    float va = 0.f;

#pragma unroll
    for (int t = 0; t < T_; ++t) {
        const int bt = t * B_ + b;
        const float* p = qpre + ((size_t)bt * C_ + h * 64 + ty * 8) * 256 + n;
        float s = 0.f;
#pragma unroll
        for (int j = 0; j < 8; ++j) {
            const float u = (p[(size_t)j * 256] - mu[j]) * sc[j] + be[j];
            v[j] = v[j] + (u - v[j]) * 0.5f;
            const float sp = (v[j] >= 1.0f) ? 1.0f : 0.0f;
            v[j] = (sp > 0.0f) ? 0.0f : v[j];
            s += sp;
        }
        red[ty][tx] = s;
        __syncthreads();
        if (ty == 0) {
            float tot = red[0][tx];
#pragma unroll
            for (int r = 1; r < 8; ++r) tot += red[r][tx];
            va = va + (tot - va) * 0.5f;
            const float asp = (va >= 1.0f) ? 1.0f : 0.0f;
            va = (asp > 0.0f) ? 0.0f : va;
            attn[((size_t)bt * 12 + h) * 256 + n] = asp;
        }
        __syncthreads();
    }
}

// ---------------------------------------------------------------------------
// BN + LIF over T -> spikes straight into blocked fp16 B layout
// (attn multiply for the k path). grid (2, 24, 16), block (128,4).
// ---------------------------------------------------------------------------
__global__ void bnlifB(const float* __restrict__ pre,
                       const float* __restrict__ attn,
                       const float* __restrict__ bnp,
                       int Cc, int Cs, int c0,
                       _Float16* __restrict__ outB, int KTout, int ktOut0)
{
    const int nb = blockIdx.x, kt = blockIdx.y, b = blockIdx.z;
    const int nn = threadIdx.x, k8 = threadIdx.y;
    const int cl = kt * 32 + k8 * 8;
    const int n = nb * 128 + nn;
    float sc[8], be[8], mu[8];
#pragma unroll
    for (int j = 0; j < 8; ++j) {
        const int c = c0 + cl + j;
        const float g = bnp[c];
        be[j] = bnp[Cs + c];
        mu[j] = bnp[2 * Cs + c];
        sc[j] = g * rsqrtf(bnp[3 * Cs + c] + 1e-5f);
    }
    float v[8];
#pragma unroll
    for (int j = 0; j < 8; ++j) v[j] = 0.f;
    const int h = cl >> 6;
#pragma unroll
    for (int t = 0; t < T_; ++t) {
        const int bt = t * B_ + b;
        const float* p = pre + ((size_t)bt * Cc + cl) * 256 + n;
        const float av = attn ? attn[((size_t)bt * 12 + h) * 256 + n] : 1.f;
        f16x8 s;
#pragma unroll
        for (int j = 0; j < 8; ++j) {
            const float u = (p[(size_t)j * 256] - mu[j]) * sc[j] + be[j];
            v[j] = v[j] + (u - v[j]) * 0.5f;
            const float sp = (v[j] >= 1.0f) ? 1.0f : 0.0f;
            v[j] = (sp > 0.0f) ? 0.0f : v[j];
            s[j] = (_Float16)(sp * av);
        }
        *(f16x8*)(outB + ((((size_t)bt * 2 + nb) * KTout + ktOut0 + kt) * 512 + k8 * 128 + nn) * 8) = s;
    }
}

extern "C" void kernel_launch(void* const* d_in, const int* in_sizes, int n_in,
                              void* d_out, int out_size, void* d_ws, size_t ws_size,
                              hipStream_t stream) {
    const float* x    = (const float*)d_in[0];
    const float* w_q  = (const float*)d_in[1];
    const float* bn_q = (const float*)d_in[2];
    const float* w_k  = (const float*)d_in[3];
    const float* bn_k = (const float*)d_in[4];
    const float* w_p  = (const float*)d_in[5];
    const float* b_p  = (const float*)d_in[6];
    const float* bn_p = (const float*)d_in[7];
    const float* w1   = (const float*)d_in[8];
    const float* b1   = (const float*)d_in[9];
    const float* bn1  = (const float*)d_in[10];
    const float* w2   = (const float*)d_in[11];
    const float* b2   = (const float*)d_in[12];
    const float* bn2  = (const float*)d_in[13];

    const size_t SZ1 = (size_t)T_ * B_ * C_ * N_;     // 12,582,912
    const size_t SZA = (size_t)T_ * B_ * 12 * N_;     // 196,608
    const size_t WCC = (size_t)C_ * C_;               // 589,824
    const size_t WCH = (size_t)C_ * CH_;              // 2,359,296

    // --- workspace layout ---
    char* w = (char*)d_ws;
    float*     qbuf  = (float*)w;     w += SZ1 * 4;      // q_pre, then Y0/Y1 (fp16)
    float*     attnb = (float*)w;     w += SZA * 4;
    _Float16*  R1    = (_Float16*)w;  w += SZ1 * 4;      // XB0/XB1 -> aB
    _Float16*  WQK0  = (_Float16*)w;  w += WCC * 2 * 2;  // [wq; wk] chunk0
    _Float16*  WQK1  = (_Float16*)w;  w += WCC * 2 * 2;
    _Float16*  WP0   = (_Float16*)w;  w += WCC * 2;
    _Float16*  WP1   = (_Float16*)w;  w += WCC * 2;
    _Float16*  W10   = (_Float16*)w;  w += WCH * 2;
    _Float16*  W11   = (_Float16*)w;  w += WCH * 2;
    _Float16*  W20   = (_Float16*)w;  w += WCH * 2;
    _Float16*  W21   = (_Float16*)w;  w += WCH * 2;
    _Float16*  s1B   = (_Float16*)w;                     // [64][2][96][4096] halfs

    _Float16* XB0 = R1;
    _Float16* XB1 = R1 + SZ1;
    _Float16* aB  = R1;                     // after q/k GEMMs (k spikes * attn)
    _Float16* YB0 = (_Float16*)qbuf;        // Y split lives in qbuf after qattn
    _Float16* YB1 = YB0 + SZ1;              // (2*SZ1 halfs == SZ1 floats: fits)

    float* dob = (float*)d_out;             // k_pre -> (consumed) -> out

    const float WS = 4096.f;                // 2^12
    const float XS = 256.f;                 // 2^8
    const float OS_G = 1.f / 1048576.f;     // 2^-20
    const float OS_S = 1.f / 4096.f;        // 2^-12

    const dim3 blk256(256);
    const dim3 blk512(512);
    const dim3 blkS(128, 4);

    // --- weight & input splits (merged launches) ---
    splitW3<<<dim3(6, 24, 3), blkS, 0, stream>>>(w_q, w_k, w_p, WQK0, WQK1, WP0, WP1, WS);
    splitW12<<<dim3(1152), blkS, 0, stream>>>(w1, w2, W10, W11, W20, W21, WS);
    splitB<<<dim3(2, 24, 64), blkS, 0, stream>>>(x, XB0, XB1, 24, XS);

    // --- merged q+k GEMM (per-bt, 3 terms): by 0..5 -> qbuf, 6..11 -> dob ---
    gemm_mfma<2, 0><<<dim3(2, 12, 64), blk256, 0, stream>>>(
        WQK0, WQK1, XB0, XB1, qbuf, dob, 6, C_, nullptr, OS_G, 24, 0, 0, 24, 24, 12);

    // --- fused q->attn; k spikes * attn into blocked fp16 ---
    qattn_kernel<<<dim3(4, 12, B_), dim3(64, 8), 0, stream>>>(qbuf, bn_q, attnb);
    bnlifB<<<dim3(2, 24, B_), blkS, 0, stream>>>(dob, attnb, bn_k, C_, C_, 0, aB, 24, 0);

    // --- p GEMM, t-batched M=32 + FUSED y-split epilogue ---
    // (qbuf's q_pre is consumed by qattn above; Y overwrites it)
    gemm_tb_lif32<0><<<dim3(2, 24, B_), blk512, 0, stream>>>(
        WP0, WP1, aB, b_p, bn_p, OS_S, 24, 24,
        x, YB0, YB1, nullptr, XS);

    // --- fused MLP layer-1 (R4 structure) ---
    gemm_mlp1<<<dim3(2, 24, B_), blk512, 0, stream>>>(
        W10, W11, YB0, YB1, b1, bn1, s1B, OS_G);

    // --- z2 GEMM, t-batched M=32 + FUSED out epilogue: out = y + spike ---
    gemm_tb_lif32<1><<<dim3(2, 24, B_), blk512, 0, stream>>>(
        W20, W21, s1B, b2, bn2, OS_S, 96, 96,
        nullptr, YB0, YB1, dob, 1.f / XS);
}

// Round 9
// 642.626 us; speedup vs baseline: 1.0859x; 1.0859x over previous
//
#include <hip/hip_runtime.h>

// T=4, B=16, C=768, H=W=16 -> N=256, Ch=3072, heads=12, d=64
#define T_ 4
#define B_ 16
#define C_ 768
#define N_ 256
#define CH_ 3072

typedef _Float16 f16x8 __attribute__((ext_vector_type(8)));
typedef _Float16 f16x4 __attribute__((ext_vector_type(4)));
typedef float f32x4 __attribute__((ext_vector_type(4)));

// ---------------------------------------------------------------------------
// Blocked operand layout (A=weights, B=activations):
//   per 128(row) x 32(k) tile: 512 chunks of 8 halfs (16B).
//   chunk index c = k8*128 + row; chunk holds k = kt*32 + k8*8 + (0..7).
// A arrays: [mb][KT][512]; B arrays: [bt][nb(2)][KT][512].
// Staging is lane-linear (global_load_lds rule) and frag ds_read_b128 is
// bank-optimal (SQ_LDS_BANK_CONFLICT == 0 measured).
//
// XCD swizzle (R4: FETCH -11%): bijective chunked remap
//   l = (l0 % 8) * (ntot/8) + l0 / 8,   decode (nb, mid, hi).
//
// FINAL configuration = measured session optimum (651 us, R5) + safe deltas:
//   qk   : per-bt 256-thr gemm_mfma<2,0>, 1536 blocks, 2 blocks/CU
//   p    : per-bt 256-thr gemm_mfma<1,0>
//   mlp1 : t-batched 8-wave, 96 MFMA/window, fused BN+LIF epilogue (189 us)
//   z2   : per-bt 256-thr gemm_mfma<1,1> (ORD=1 co-locates W2 sharers on XCD)
//   elementwise LIF stages as separate memory-bound kernels.
// Measured-negative alternatives (do not revisit without new evidence):
//   32x32 MFMA shape (+58 us), counted-vmcnt 4-phase mlp1 (+6), t-batched
//   512-thr qk/p/z2 (+44), fused-LIF epilogues at 192 blocks (+14) and at
//   M=32/768 blocks (+47, MfmaUtil 33% - window overhead dominates).
// ---------------------------------------------------------------------------

__device__ __forceinline__ int xcd_swizzle_linear()
{
    const int ntot = gridDim.x * gridDim.y * gridDim.z;
    const int l0 = blockIdx.x + gridDim.x * (blockIdx.y + gridDim.y * blockIdx.z);
    return (l0 & 7) * (ntot >> 3) + (l0 >> 3);   // ntot % 8 == 0 for all launches
}

// 4-wave staging: each wave stages 128 chunks (2 x 16B/lane instrs).
__device__ __forceinline__ void stage_tile(const _Float16* g, _Float16* l,
                                           int wv, int ln)
{
#pragma unroll
    for (int i = 0; i < 2; ++i) {
        const int c = wv * 128 + i * 64;
        __builtin_amdgcn_global_load_lds(
            (const __attribute__((address_space(1))) void*)(g + (size_t)(c + ln) * 8),
            (__attribute__((address_space(3))) void*)(l + (size_t)c * 8),
            16, 0, 0);
    }
}

// 8-wave staging: each wave stages 64 chunks (1 x 16B/lane instr).
__device__ __forceinline__ void stage_tile8(const _Float16* g, _Float16* l,
                                            int wv, int ln)
{
    const int c = wv * 64;
    __builtin_amdgcn_global_load_lds(
        (const __attribute__((address_space(1))) void*)(g + (size_t)(c + ln) * 8),
        (__attribute__((address_space(3))) void*)(l + (size_t)c * 8),
        16, 0, 0);
}

// ---------------------------------------------------------------------------
// Per-bt MFMA GEMM: O[bt, m, n] = oscale * sum_k (A0+A1)[m,k]*(B0[+B1])[k,n]
// (+bias). NB=2: general fp32 operand (A0B0, A1B0, A0B1); NB=1: exact spikes.
// Tile 128x128, 4 waves of 64x64 (4x4 mfma_f32_16x16x32_f16), double-buffered
// LDS with stage-ahead: stage(kt+1) issued right after the barrier, compute
// kt from the other buffer; the single __syncthreads per kt drains the stage
// issued one iteration earlier (global->LDS latency hides under MFMA).
// ORD=0: logical (nb, by[midN], bt);  ORD=1: logical (nb, bt[midN], by).
// Dual output: by < splitBy -> Oq, else Ok (m rebased). M = rows per output.
// ---------------------------------------------------------------------------
template <int NB, int ORD>
__global__ __launch_bounds__(256) void gemm_mfma(
    const _Float16* __restrict__ A0, const _Float16* __restrict__ A1,
    const _Float16* __restrict__ B0, const _Float16* __restrict__ B1,
    float* __restrict__ Oq, float* __restrict__ Ok, int splitBy, int M,
    const float* __restrict__ bias, float oscale,
    int KTA, int ktA0, int mbA0, int KTB, int nkt, int midN)
{
    const int l = xcd_swizzle_linear();
    const int nb = l & 1;
    const int mid = (l >> 1) % midN;
    const int hi  = (l >> 1) / midN;
    const int by = (ORD == 0) ? mid : hi;
    const int bt = (ORD == 0) ? hi  : mid;
    const int mbA = mbA0 + by;

    __shared__ _Float16 lds[2][(2 + NB) * 4096];

    const int tid = threadIdx.x;
    const int wv = tid >> 6;
    const int ln = tid & 63;
    const int mw = (wv >> 1) * 64;
    const int nw = (wv & 1) * 64;

    f32x4 acc[4][4];
#pragma unroll
    for (int i = 0; i < 4; ++i)
#pragma unroll
        for (int j = 0; j < 4; ++j)
            acc[i][j] = (f32x4){0.f, 0.f, 0.f, 0.f};

    const _Float16* ga0 = A0 + ((size_t)mbA * KTA + ktA0) * 4096;
    const _Float16* ga1 = A1 + ((size_t)mbA * KTA + ktA0) * 4096;
    const _Float16* gb0 = B0 + (((size_t)bt * 2 + nb) * KTB) * 4096;
    const _Float16* gb1 = (NB == 2) ? B1 + (((size_t)bt * 2 + nb) * KTB) * 4096 : nullptr;

    const int ca = (ln >> 4) * 128 + mw + (ln & 15);   // A frag chunk base
    const int cb = (ln >> 4) * 128 + nw + (ln & 15);   // B frag chunk base

    _Float16* Lc = &lds[0][0];
    _Float16* Ln = &lds[1][0];

    // prologue: stage kt=0 into buffer 0
    stage_tile(ga0, Lc, wv, ln);
    stage_tile(ga1, Lc + 4096, wv, ln);
    stage_tile(gb0, Lc + 2 * 4096, wv, ln);
    if (NB == 2) stage_tile(gb1, Lc + 3 * 4096, wv, ln);

    for (int kt = 0; kt < nkt; ++kt) {
        __syncthreads();   // drains vmcnt: Lc staged; fences last iter's Ln reads
        if (kt + 1 < nkt) {
            stage_tile(ga0 + 4096, Ln, wv, ln);
            stage_tile(ga1 + 4096, Ln + 4096, wv, ln);
            stage_tile(gb0 + 4096, Ln + 2 * 4096, wv, ln);
            if (NB == 2) stage_tile(gb1 + 4096, Ln + 3 * 4096, wv, ln);
        }

        f16x8 a0[4], a1[4];
#pragma unroll
        for (int mt = 0; mt < 4; ++mt) {
            a0[mt] = *(const f16x8*)&Lc[(ca + mt * 16) * 8];
            a1[mt] = *(const f16x8*)&Lc[4096 + (ca + mt * 16) * 8];
        }
#pragma unroll
        for (int nt = 0; nt < 4; ++nt) {
            const f16x8 b0 = *(const f16x8*)&Lc[2 * 4096 + (cb + nt * 16) * 8];
            f16x8 b1;
            if (NB == 2) b1 = *(const f16x8*)&Lc[3 * 4096 + (cb + nt * 16) * 8];
#pragma unroll
            for (int mt = 0; mt < 4; ++mt) {
                acc[mt][nt] = __builtin_amdgcn_mfma_f32_16x16x32_f16(a0[mt], b0, acc[mt][nt], 0, 0, 0);
                acc[mt][nt] = __builtin_amdgcn_mfma_f32_16x16x32_f16(a1[mt], b0, acc[mt][nt], 0, 0, 0);
                if (NB == 2)
                    acc[mt][nt] = __builtin_amdgcn_mfma_f32_16x16x32_f16(a0[mt], b1, acc[mt][nt], 0, 0, 0);
            }
        }
        ga0 += 4096; ga1 += 4096; gb0 += 4096;
        if (NB == 2) gb1 += 4096;
        _Float16* tmp = Lc; Lc = Ln; Ln = tmp;
    }

    // Epilogue. C/D layout: col(n) = lane&15, row(m) = (lane>>4)*4 + reg.
    float* Obase = (by < splitBy) ? Oq : Ok;
    const int byl = (by < splitBy) ? by : by - splitBy;
    float* Ob = Obase + (size_t)bt * M * 256;
    const int lm = (ln >> 4) * 4;
    const int lnn = ln & 15;
#pragma unroll
    for (int mt = 0; mt < 4; ++mt) {
#pragma unroll
        for (int r = 0; r < 4; ++r) {
            const int m = byl * 128 + mw + mt * 16 + lm + r;
            const float bb = bias ? bias[m] : 0.0f;
#pragma unroll
            for (int nt = 0; nt < 4; ++nt) {
                const int n = nb * 128 + nw + nt * 16 + lnn;
                Ob[(size_t)m * 256 + n] = acc[mt][nt][r] * oscale + bb;
            }
        }
    }
}

// ---------------------------------------------------------------------------
// Fused MLP layer-1 (best measured, 189 us): s1 = LIF(BN1(w1 @ y + b1)),
// ALL 4 time steps in ONE K-pass. 512 threads (8 waves, 2m x 4n, per-wave
// 64x32/t). Per kt: A0/A1 staged ONCE (shared across t) + 4t x {Y0,Y1}
// tiles; 96 MFMA per wave per barrier window. acc[t][mt][nt] keeps all 4
// t's pre-activations; BN+LIF run in the epilogue (no persistent membrane
// regs in the main loop). LDS: 2 x 80 KB = 160 KB dbuf stage-ahead.
// ---------------------------------------------------------------------------
__global__ __launch_bounds__(512, 2) void gemm_mlp1(
    const _Float16* __restrict__ A0, const _Float16* __restrict__ A1,
    const _Float16* __restrict__ B0, const _Float16* __restrict__ B1,
    const float* __restrict__ bias, const float* __restrict__ bnp,
    _Float16* __restrict__ outB, float oscale)
{
    const int l = xcd_swizzle_linear();            // 768 blocks, chunk=96/XCD
    const int nb = l & 1;                          // 0..1
    const int by = (l >> 1) % 24;                  // 0..23
    const int b  = (l >> 1) / 24;                  // 0..15

    __shared__ _Float16 lds[2][10 * 4096];   // 163840 B = full 160 KiB LDS

    const int tid = threadIdx.x;
    const int wv = tid >> 6;              // 0..7
    const int ln = tid & 63;
    const int mw = (wv >> 2) * 64;        // 2 m-groups of 64
    const int nw = (wv & 3) * 32;         // 4 n-groups of 32
    const int lm = (ln >> 4) * 4;
    const int lnn = ln & 15;

    const _Float16* gA0 = A0 + ((size_t)by * 24) * 4096;
    const _Float16* gA1 = A1 + ((size_t)by * 24) * 4096;
    const _Float16* gB0t[4];
    const _Float16* gB1t[4];
#pragma unroll
    for (int t = 0; t < 4; ++t) {
        const int bt = t * B_ + b;
        gB0t[t] = B0 + (((size_t)bt * 2 + nb) * 24) * 4096;
        gB1t[t] = B1 + (((size_t)bt * 2 + nb) * 24) * 4096;
    }

    f32x4 acc[4][4][2];                   // [t][mt][nt]
#pragma unroll
    for (int t = 0; t < 4; ++t)
#pragma unroll
        for (int i = 0; i < 4; ++i)
#pragma unroll
            for (int j = 0; j < 2; ++j)
                acc[t][i][j] = (f32x4){0.f, 0.f, 0.f, 0.f};

    const int ca = (ln >> 4) * 128 + mw + lnn;   // A frag chunk base
    const int cb = (ln >> 4) * 128 + nw + lnn;   // B frag chunk base

    _Float16* Lc = &lds[0][0];
    _Float16* Ln = &lds[1][0];

    // prologue: stage kt=0
    stage_tile8(gA0, Lc, wv, ln);
    stage_tile8(gA1, Lc + 4096, wv, ln);
#pragma unroll
    for (int t = 0; t < 4; ++t) {
        stage_tile8(gB0t[t], Lc + (2 + 2 * t) * 4096, wv, ln);
        stage_tile8(gB1t[t], Lc + (3 + 2 * t) * 4096, wv, ln);
    }

    for (int kt = 0; kt < 24; ++kt) {
        __syncthreads();   // drains vmcnt: Lc staged; fences last iter's Ln reads
        if (kt < 23) {
            const size_t o = (size_t)(kt + 1) * 4096;
            stage_tile8(gA0 + o, Ln, wv, ln);
            stage_tile8(gA1 + o, Ln + 4096, wv, ln);
#pragma unroll
            for (int t = 0; t < 4; ++t) {
                stage_tile8(gB0t[t] + o, Ln + (2 + 2 * t) * 4096, wv, ln);
                stage_tile8(gB1t[t] + o, Ln + (3 + 2 * t) * 4096, wv, ln);
            }
        }

        f16x8 a0[4], a1[4];
#pragma unroll
        for (int mt = 0; mt < 4; ++mt) {
            a0[mt] = *(const f16x8*)&Lc[(ca + mt * 16) * 8];
            a1[mt] = *(const f16x8*)&Lc[4096 + (ca + mt * 16) * 8];
        }
#pragma unroll
        for (int t = 0; t < 4; ++t) {
#pragma unroll
            for (int nt = 0; nt < 2; ++nt) {
                const f16x8 b0 = *(const f16x8*)&Lc[(2 + 2 * t) * 4096 + (cb + nt * 16) * 8];
                const f16x8 b1 = *(const f16x8*)&Lc[(3 + 2 * t) * 4096 + (cb + nt * 16) * 8];
#pragma unroll
                for (int mt = 0; mt < 4; ++mt) {
                    acc[t][mt][nt] = __builtin_amdgcn_mfma_f32_16x16x32_f16(a0[mt], b0, acc[t][mt][nt], 0, 0, 0);
                    acc[t][mt][nt] = __builtin_amdgcn_mfma_f32_16x16x32_f16(a1[mt], b0, acc[t][mt][nt], 0, 0, 0);
                    acc[t][mt][nt] = __builtin_amdgcn_mfma_f32_16x16x32_f16(a0[mt], b1, acc[t][mt][nt], 0, 0, 0);
                }
            }
        }
        _Float16* tmp = Lc; Lc = Ln; Ln = tmp;
    }

    // folded BN constants: u = acc*(oscale*sc) + ((bias-mu)*sc + be)
    float Af[16], Bf[16];
#pragma unroll
    for (int mt = 0; mt < 4; ++mt)
#pragma unroll
        for (int r = 0; r < 4; ++r) {
            const int c = by * 128 + mw + mt * 16 + lm + r;
            const float g  = bnp[c];
            const float be = bnp[CH_ + c];
            const float mu = bnp[2 * CH_ + c];
            const float va = bnp[3 * CH_ + c];
            const float sc = g * rsqrtf(va + 1e-5f);
            Af[mt * 4 + r] = oscale * sc;
            Bf[mt * 4 + r] = (bias[c] - mu) * sc + be;
        }

    // BN + LIF over t -> blocked fp16 spikes (s1B, KT=96)
#pragma unroll
    for (int mt = 0; mt < 4; ++mt) {
        const int c0m = by * 128 + mw + mt * 16 + lm;   // lane's first channel
        const int kt_out = c0m >> 5;
        const int k8 = (c0m & 31) >> 3;
        const int j0 = c0m & 7;                         // 0 or 4
#pragma unroll
        for (int nt = 0; nt < 2; ++nt) {
            const int row = nw + nt * 16 + lnn;
            float vv[4] = {0.f, 0.f, 0.f, 0.f};
#pragma unroll
            for (int t = 0; t < 4; ++t) {
                const int bt = t * B_ + b;
                _Float16* ob = outB + (((size_t)bt * 2 + nb) * 96) * 4096;
                f16x4 hh;
#pragma unroll
                for (int r = 0; r < 4; ++r) {
                    const float u = acc[t][mt][nt][r] * Af[mt * 4 + r] + Bf[mt * 4 + r];
                    float xv = vv[r];
                    xv = xv + (u - xv) * 0.5f;
                    const float sp = (xv >= 1.0f) ? 1.0f : 0.0f;
                    vv[r] = (sp > 0.0f) ? 0.0f : xv;
                    hh[r] = (_Float16)sp;
                }
                *(f16x4*)(ob + ((size_t)kt_out * 512 + k8 * 128 + row) * 8 + j0) = hh;
            }
        }
    }
}

// ---------------------------------------------------------------------------
// Merged weight split for w1 (576 block-units) + w2 (576): one launch.
// bi < 576: w1 [3072][768], KT=24, mb=bi%24;  else w2 [768][3072], KT=96.
// ---------------------------------------------------------------------------
__global__ void splitW12(const float* __restrict__ w1s, const float* __restrict__ w2s,
                         _Float16* __restrict__ C10, _Float16* __restrict__ C11,
                         _Float16* __restrict__ C20, _Float16* __restrict__ C21,
                         float scale)
{
    const int bi = blockIdx.x;
    const float* W; _Float16 *C0, *C1; int mb, kt, KT, ldW;
    if (bi < 576) { W = w1s; C0 = C10; C1 = C11; mb = bi % 24; kt = bi / 24; KT = 24; ldW = C_; }
    else          { const int bj = bi - 576;
                    W = w2s; C0 = C20; C1 = C21; mb = bj % 6;  kt = bj / 6;  KT = 96; ldW = CH_; }
    const int mm = threadIdx.x, k8 = threadIdx.y;
    const float* src = W + (size_t)(mb * 128 + mm) * ldW + kt * 32 + k8 * 8;
    const size_t cb = (((size_t)mb * KT + kt) * 512 + k8 * 128 + mm) * 8;
    f16x8 h0, h1;
#pragma unroll
    for (int j = 0; j < 8; ++j) {
        const float x = src[j] * scale;
        const _Float16 h = (_Float16)x;
        h0[j] = h;
        h1[j] = (_Float16)(x - (float)h);
    }
    *(f16x8*)(C0 + cb) = h0;
    *(f16x8*)(C1 + cb) = h1;
}

// ---------------------------------------------------------------------------
// Merged split of the three CxC weights: z=0 -> w_q (WQK rows 0..767),
// z=1 -> w_k (WQK rows 768..1535), z=2 -> w_p. grid (6, 24, 3), block (128,4).
// ---------------------------------------------------------------------------
__global__ void splitW3(const float* __restrict__ wq, const float* __restrict__ wk,
                        const float* __restrict__ wp,
                        _Float16* __restrict__ WQK0, _Float16* __restrict__ WQK1,
                        _Float16* __restrict__ WP0,  _Float16* __restrict__ WP1,
                        float scale)
{
    const size_t WCC = (size_t)C_ * C_;
    const int z = blockIdx.z;
    const float* W;
    _Float16 *C0, *C1;
    if (z == 0)      { W = wq; C0 = WQK0;       C1 = WQK1; }
    else if (z == 1) { W = wk; C0 = WQK0 + WCC; C1 = WQK1 + WCC; }
    else             { W = wp; C0 = WP0;        C1 = WP1; }
    const int mb = blockIdx.x, kt = blockIdx.y;
    const int mm = threadIdx.x, k8 = threadIdx.y;
    const float* src = W + (size_t)(mb * 128 + mm) * C_ + kt * 32 + k8 * 8;
    const size_t cb = (((size_t)mb * 24 + kt) * 512 + k8 * 128 + mm) * 8;
    f16x8 h0, h1;
#pragma unroll
    for (int j = 0; j < 8; ++j) {
        const float x = src[j] * scale;
        const _Float16 h = (_Float16)x;
        h0[j] = h;
        h1[j] = (_Float16)(x - (float)h);
    }
    *(f16x8*)(C0 + cb) = h0;
    *(f16x8*)(C1 + cb) = h1;
}

// ---------------------------------------------------------------------------
// Activation split: X fp32 [64][K][256] -> 2 fp16 chunk arrays (blocked B),
// scaled by 2^8. grid (2, KT, 64), block (128,4).
// ---------------------------------------------------------------------------
__global__ void splitB(const float* __restrict__ X,
                       _Float16* __restrict__ C0, _Float16* __restrict__ C1,
                       int KT, float scale)
{
    const int nb = blockIdx.x, kt = blockIdx.y, bt = blockIdx.z;
    const int nn = threadIdx.x, k8 = threadIdx.y;
    const int K = KT * 32;
    const float* src = X + ((size_t)bt * K + kt * 32 + k8 * 8) * 256 + nb * 128 + nn;
    const size_t cb = ((((size_t)bt * 2 + nb) * KT + kt) * 512 + k8 * 128 + nn) * 8;
    f16x8 h0, h1;
#pragma unroll
    for (int j = 0; j < 8; ++j) {
        const float x = src[(size_t)j * 256] * scale;
        const _Float16 h = (_Float16)x;
        h0[j] = h;
        h1[j] = (_Float16)(x - (float)h);
    }
    *(f16x8*)(C0 + cb) = h0;
    *(f16x8*)(C1 + cb) = h1;
}

// ---------------------------------------------------------------------------
// Fused q path: BN+LIF on q_pre, head-sum over d=64, attn LIF -> attn spikes.
// q spikes never materialized. grid (4, 12, 16), block (64, 8).
// ---------------------------------------------------------------------------
__global__ __launch_bounds__(512) void qattn_kernel(
    const float* __restrict__ qpre, const float* __restrict__ bnp,
    float* __restrict__ attn)
{
    const int tx = threadIdx.x, ty = threadIdx.y;
    const int n = blockIdx.x * 64 + tx;
    const int h = blockIdx.y, b = blockIdx.z;
    __shared__ float red[8][64];

    float sc[8], be[8], mu[8];
#pragma unroll
    for (int j = 0; j < 8; ++j) {
        const int c = h * 64 + ty * 8 + j;
        const float g = bnp[c];
        be[j] = bnp[C_ + c];
        mu[j] = bnp[2 * C_ + c];
        sc[j] = g * rsqrtf(bnp[3 * C_ + c] + 1e-5f);
    }
    float v[8];
#pragma unroll
    for (int j = 0; j < 8; ++j) v[j] = 0.f;
    float va = 0.f;

#pragma unroll
    for (int t = 0; t < T_; ++t) {
        const int bt = t * B_ + b;
        const float* p = qpre + ((size_t)bt * C_ + h * 64 + ty * 8) * 256 + n;
        float s = 0.f;
#pragma unroll
        for (int j = 0; j < 8; ++j) {
            const float u = (p[(size_t)j * 256] - mu[j]) * sc[j] + be[j];
            v[j] = v[j] + (u - v[j]) * 0.5f;
            const float sp = (v[j] >= 1.0f) ? 1.0f : 0.0f;
            v[j] = (sp > 0.0f) ? 0.0f : v[j];
            s += sp;
        }
        red[ty][tx] = s;
        __syncthreads();
        if (ty == 0) {
            float tot = red[0][tx];
#pragma unroll
            for (int r = 1; r < 8; ++r) tot += red[r][tx];
            va = va + (tot - va) * 0.5f;
            const float asp = (va >= 1.0f) ? 1.0f : 0.0f;
            va = (asp > 0.0f) ? 0.0f : va;
            attn[((size_t)bt * 12 + h) * 256 + n] = asp;
        }
        __syncthreads();
    }
}

// ---------------------------------------------------------------------------
// BN + LIF over T -> spikes straight into blocked fp16 B layout
// (attn multiply for the k path). grid (2, 24, 16), block (128,4).
// ---------------------------------------------------------------------------
__global__ void bnlifB(const float* __restrict__ pre,
                       const float* __restrict__ attn,
                       const float* __restrict__ bnp,
                       int Cc, int Cs, int c0,
                       _Float16* __restrict__ outB, int KTout, int ktOut0)
{
    const int nb = blockIdx.x, kt = blockIdx.y, b = blockIdx.z;
    const int nn = threadIdx.x, k8 = threadIdx.y;
    const int cl = kt * 32 + k8 * 8;
    const int n = nb * 128 + nn;
    float sc[8], be[8], mu[8];
#pragma unroll
    for (int j = 0; j < 8; ++j) {
        const int c = c0 + cl + j;
        const float g = bnp[c];
        be[j] = bnp[Cs + c];
        mu[j] = bnp[2 * Cs + c];
        sc[j] = g * rsqrtf(bnp[3 * Cs + c] + 1e-5f);
    }
    float v[8];
#pragma unroll
    for (int j = 0; j < 8; ++j) v[j] = 0.f;
    const int h = cl >> 6;
#pragma unroll
    for (int t = 0; t < T_; ++t) {
        const int bt = t * B_ + b;
        const float* p = pre + ((size_t)bt * Cc + cl) * 256 + n;
        const float av = attn ? attn[((size_t)bt * 12 + h) * 256 + n] : 1.f;
        f16x8 s;
#pragma unroll
        for (int j = 0; j < 8; ++j) {
            const float u = (p[(size_t)j * 256] - mu[j]) * sc[j] + be[j];
            v[j] = v[j] + (u - v[j]) * 0.5f;
            const float sp = (v[j] >= 1.0f) ? 1.0f : 0.0f;
            v[j] = (sp > 0.0f) ? 0.0f : v[j];
            s[j] = (_Float16)(sp * av);
        }
        *(f16x8*)(outB + ((((size_t)bt * 2 + nb) * KTout + ktOut0 + kt) * 512 + k8 * 128 + nn) * 8) = s;
    }
}

// ---------------------------------------------------------------------------
// Fused y path: y = x + spike(bn_p(p_pre)); writes ONLY the scaled fp16
// 2-chunk blocked split of y (y fp32 is never materialized; the final stage
// reconstructs y = (Y0+Y1)/xscale exactly to ~2^-24 rel).
// grid (2, 24, 16), block (128,4).
// ---------------------------------------------------------------------------
__global__ void bnlif_y_split(const float* __restrict__ ppre,
                              const float* __restrict__ x,
                              const float* __restrict__ bnp,
                              _Float16* __restrict__ Y0, _Float16* __restrict__ Y1,
                              float xscale)
{
    const int nb = blockIdx.x, kt = blockIdx.y, b = blockIdx.z;
    const int nn = threadIdx.x, k8 = threadIdx.y;
    const int cl = kt * 32 + k8 * 8;
    const int n = nb * 128 + nn;
    float sc[8], be[8], mu[8];
#pragma unroll
    for (int j = 0; j < 8; ++j) {
        const int c = cl + j;
        const float g = bnp[c];
        be[j] = bnp[C_ + c];
        mu[j] = bnp[2 * C_ + c];
        sc[j] = g * rsqrtf(bnp[3 * C_ + c] + 1e-5f);
    }
    float v[8];
#pragma unroll
    for (int j = 0; j < 8; ++j) v[j] = 0.f;
#pragma unroll
    for (int t = 0; t < T_; ++t) {
        const int bt = t * B_ + b;
        const size_t off = ((size_t)bt * C_ + cl) * 256 + n;
        const float* p = ppre + off;
        const float* xx = x + off;
        f16x8 h0, h1;
#pragma unroll
        for (int j = 0; j < 8; ++j) {
            const float u = (p[(size_t)j * 256] - mu[j]) * sc[j] + be[j];
            v[j] = v[j] + (u - v[j]) * 0.5f;
            const float sp = (v[j] >= 1.0f) ? 1.0f : 0.0f;
            v[j] = (sp > 0.0f) ? 0.0f : v[j];
            const float ys = (xx[(size_t)j * 256] + sp) * xscale;
            const _Float16 hh = (_Float16)ys;
            h0[j] = hh;
            h1[j] = (_Float16)(ys - (float)hh);
        }
        const size_t cb = ((((size_t)bt * 2 + nb) * 24 + kt) * 512 + k8 * 128 + nn) * 8;
        *(f16x8*)(Y0 + cb) = h0;
        *(f16x8*)(Y1 + cb) = h1;
    }
}

// ---------------------------------------------------------------------------
// Final stage: out = y + spike(bn2(z2)), y reconstructed from the blocked
// fp16 split (y = (Y0+Y1)*yinv). grid (2, 24, 16), block (128,4).
// ---------------------------------------------------------------------------
__global__ void bnlif_out(const float* __restrict__ z2,
                          const _Float16* __restrict__ Y0,
                          const _Float16* __restrict__ Y1,
                          const float* __restrict__ bnp,
                          float* __restrict__ out, float yinv)
{
    const int nb = blockIdx.x, kt = blockIdx.y, b = blockIdx.z;
    const int nn = threadIdx.x, k8 = threadIdx.y;
    const int cl = kt * 32 + k8 * 8;
    const int n = nb * 128 + nn;
    float sc[8], be[8], mu[8];
#pragma unroll
    for (int j = 0; j < 8; ++j) {
        const int c = cl + j;
        const float g = bnp[c];
        be[j] = bnp[C_ + c];
        mu[j] = bnp[2 * C_ + c];
        sc[j] = g * rsqrtf(bnp[3 * C_ + c] + 1e-5f);
    }
    float v[8];
#pragma unroll
    for (int j = 0; j < 8; ++j) v[j] = 0.f;
#pragma unroll
    for (int t = 0; t < T_; ++t) {
        const int bt = t * B_ + b;
        const size_t off = ((size_t)bt * C_ + cl) * 256 + n;
        const float* zp = z2 + off;
        float* op = out + off;
        const size_t ycb = ((((size_t)bt * 2 + nb) * 24 + kt) * 512 + k8 * 128 + nn) * 8;
        const f16x8 y0 = *(const f16x8*)(Y0 + ycb);
        const f16x8 y1 = *(const f16x8*)(Y1 + ycb);
#pragma unroll
        for (int j = 0; j < 8; ++j) {
            const float u = (zp[(size_t)j * 256] - mu[j]) * sc[j] + be[j];
            v[j] = v[j] + (u - v[j]) * 0.5f;
            const float sp = (v[j] >= 1.0f) ? 1.0f : 0.0f;
            v[j] = (sp > 0.0f) ? 0.0f : v[j];
            const float y = ((float)y0[j] + (float)y1[j]) * yinv;
            op[(size_t)j * 256] = y + sp;
        }
    }
}

extern "C" void kernel_launch(void* const* d_in, const int* in_sizes, int n_in,
                              void* d_out, int out_size, void* d_ws, size_t ws_size,
                              hipStream_t stream) {
    const float* x    = (const float*)d_in[0];
    const float* w_q  = (const float*)d_in[1];
    const float* bn_q = (const float*)d_in[2];
    const float* w_k  = (const float*)d_in[3];
    const float* bn_k = (const float*)d_in[4];
    const float* w_p  = (const float*)d_in[5];
    const float* b_p  = (const float*)d_in[6];
    const float* bn_p = (const float*)d_in[7];
    const float* w1   = (const float*)d_in[8];
    const float* b1   = (const float*)d_in[9];
    const float* bn1  = (const float*)d_in[10];
    const float* w2   = (const float*)d_in[11];
    const float* b2   = (const float*)d_in[12];
    const float* bn2  = (const float*)d_in[13];

    const size_t SZ1 = (size_t)T_ * B_ * C_ * N_;     // 12,582,912
    const size_t SZA = (size_t)T_ * B_ * 12 * N_;     // 196,608
    const size_t WCC = (size_t)C_ * C_;               // 589,824
    const size_t WCH = (size_t)C_ * CH_;              // 2,359,296

    // --- workspace layout ---
    char* w = (char*)d_ws;
    float*     qbuf  = (float*)w;     w += SZ1 * 4;      // q_pre -> p_pre
    float*     attnb = (float*)w;     w += SZA * 4;
    _Float16*  R1    = (_Float16*)w;  w += SZ1 * 4;      // XB0/XB1 -> aB -> YB0/YB1
    _Float16*  WQK0  = (_Float16*)w;  w += WCC * 2 * 2;  // [wq; wk] chunk0
    _Float16*  WQK1  = (_Float16*)w;  w += WCC * 2 * 2;
    _Float16*  WP0   = (_Float16*)w;  w += WCC * 2;
    _Float16*  WP1   = (_Float16*)w;  w += WCC * 2;
    _Float16*  W10   = (_Float16*)w;  w += WCH * 2;
    _Float16*  W11   = (_Float16*)w;  w += WCH * 2;
    _Float16*  W20   = (_Float16*)w;  w += WCH * 2;
    _Float16*  W21   = (_Float16*)w;  w += WCH * 2;
    _Float16*  s1B   = (_Float16*)w;                     // [64][2][96][4096] halfs

    _Float16* XB0 = R1;
    _Float16* XB1 = R1 + SZ1;
    _Float16* aB  = R1;                     // after q/k GEMMs (k spikes * attn)
    _Float16* YB0 = R1;                     // after p GEMM
    _Float16* YB1 = R1 + SZ1;

    float* dob = (float*)d_out;             // k_pre -> (consumed) -> z2 -> out

    const float WS = 4096.f;                // 2^12
    const float XS = 256.f;                 // 2^8
    const float OS_G = 1.f / 1048576.f;     // 2^-20
    const float OS_S = 1.f / 4096.f;        // 2^-12

    const dim3 blk256(256);
    const dim3 blk512(512);
    const dim3 blkS(128, 4);

    // --- weight & input splits (merged launches) ---
    splitW3<<<dim3(6, 24, 3), blkS, 0, stream>>>(w_q, w_k, w_p, WQK0, WQK1, WP0, WP1, WS);
    splitW12<<<dim3(1152), blkS, 0, stream>>>(w1, w2, W10, W11, W20, W21, WS);
    splitB<<<dim3(2, 24, 64), blkS, 0, stream>>>(x, XB0, XB1, 24, XS);

    // --- merged q+k GEMM (per-bt, 3 terms): by 0..5 -> qbuf, 6..11 -> dob ---
    gemm_mfma<2, 0><<<dim3(2, 12, 64), blk256, 0, stream>>>(
        WQK0, WQK1, XB0, XB1, qbuf, dob, 6, C_, nullptr, OS_G, 24, 0, 0, 24, 24, 12);

    // --- fused q->attn; k spikes * attn into blocked fp16 ---
    qattn_kernel<<<dim3(4, 12, B_), dim3(64, 8), 0, stream>>>(qbuf, bn_q, attnb);
    bnlifB<<<dim3(2, 24, B_), blkS, 0, stream>>>(dob, attnb, bn_k, C_, C_, 0, aB, 24, 0);

    // --- p = w_p @ a + b_p (spike, 2 terms); Y split of y = x + spike(bn_p(p)) ---
    gemm_mfma<1, 0><<<dim3(2, 6, 64), blk256, 0, stream>>>(
        WP0, WP1, aB, nullptr, qbuf, nullptr, 9999, C_, b_p, OS_S, 24, 0, 0, 24, 24, 6);
    bnlif_y_split<<<dim3(2, 24, B_), blkS, 0, stream>>>(qbuf, x, bn_p, YB0, YB1, XS);

    // --- fused MLP layer-1 (best structure: 96 MFMA/window, 189 us) ---
    gemm_mlp1<<<dim3(2, 24, B_), blk512, 0, stream>>>(
        W10, W11, YB0, YB1, b1, bn1, s1B, OS_G);

    // --- z2 = w2 @ s1 + b2, single K=3072 pass; ORD=1 co-locates A sharers ---
    gemm_mfma<1, 1><<<dim3(2, 6, 64), blk256, 0, stream>>>(
        W20, W21, s1B, nullptr, dob, nullptr, 9999, C_, b2, OS_S, 96, 0, 0, 96, 96, 64);

    // --- out = y + spike(bn2(z2)), y from Y0+Y1 ---
    bnlif_out<<<dim3(2, 24, B_), blkS, 0, stream>>>(dob, YB0, YB1, bn2, dob, 1.f / XS);
}